// Round 2
// baseline (22810.416 us; speedup 1.0000x reference)
//
#include <hip/hip_runtime.h>
#include <math.h>

#define ND 64
#define PAD 65
#define NN 4096
#define NB 8192

// ws layout (floats)
#define OFF_MEANPART ((size_t)0)        // 32*4096
#define OFF_MEANA    ((size_t)131072)
#define OFF_S        ((size_t)135168)
#define OFF_SI       ((size_t)139264)
#define OFF_SS       ((size_t)143360)
#define OFF_TBAR     ((size_t)147456)
#define OFF_MI       ((size_t)151552)
#define OFF_P        ((size_t)155648)
#define OFF_VARPART  ((size_t)155712)   // 1024
#define OFF_LAM      ((size_t)156736)   // NB*ND = 524288
#define OFF_TPART    ((size_t)681024)   // G2*4096

typedef int v2i __attribute__((ext_vector_type(2)));

// ---------------------------------------------------------------------------
// lane-exchange primitives (VALU where possible, exact everywhere)
// ---------------------------------------------------------------------------
template<int CTRL>
__device__ __forceinline__ float dppf(float x) {
  return __builtin_bit_cast(float,
      __builtin_amdgcn_mov_dpp(__builtin_bit_cast(int, x), CTRL, 0xF, 0xF, true));
}
__device__ __forceinline__ float bperm_f(int pa, float x) {
  return __builtin_bit_cast(float,
      __builtin_amdgcn_ds_bpermute(pa, __builtin_bit_cast(int, x)));
}
#if __has_builtin(__builtin_amdgcn_permlane16_swap)
#define HAVE_PL16 1
// y[lane] = x[lane^16], convention-independent and BIT-EXACT:
// swap(x,x) yields the two 16-row-swapped broadcasts {A,B} in some order;
// A+B-x in integer arithmetic == x[lane^16] exactly (wraparound-safe).
__device__ __forceinline__ float pl16x(float x) {
  int xi = __builtin_bit_cast(int, x);
  v2i pr = __builtin_amdgcn_permlane16_swap(xi, xi, false, false);
  unsigned r = (unsigned)pr.x + (unsigned)pr.y - (unsigned)xi;
  return __builtin_bit_cast(float, (int)r);
}
#endif

// ---------------------------------------------------------------------------
// Two-sided LDS Jacobi (256 threads, one 64x64 matrix) for the few singles.
// ---------------------------------------------------------------------------
__device__ void jacobi2s(float (&A)[ND][PAD], float (&V)[ND][PAD], int tid) {
  __shared__ float cs_[32], sn_[32];
  __shared__ int   pp_[32], qq_[32];
  __shared__ int   rotcnt_;
  __shared__ float fro2_;
  __shared__ float red_[4];

  __syncthreads();
  float loc = 0.f;
  for (int e = tid; e < NN; e += 256) { float a = A[e >> 6][e & 63]; loc += a * a; }
  for (int o = 32; o; o >>= 1) loc += __shfl_down(loc, o);
  if ((tid & 63) == 0) red_[tid >> 6] = loc;
  __syncthreads();
  if (tid == 0) fro2_ = red_[0] + red_[1] + red_[2] + red_[3];
  __syncthreads();
  float fro2 = fro2_;

  for (int sweep = 0; sweep < 20; ++sweep) {
    if (tid == 0) rotcnt_ = 0;
    __syncthreads();
    for (int r = 0; r < 63; ++r) {
      if (tid < 32) {
        int p, q;
        if (tid == 0) { p = 63; q = r; }
        else { p = (r + tid) % 63; q = (r + 63 - tid) % 63; }
        if (p > q) { int t0 = p; p = q; q = t0; }
        pp_[tid] = p; qq_[tid] = q;
        float app = A[p][p], aqq = A[q][q], apq = A[p][q];
        float thr = fmaxf(1e-12f * fabsf(app * aqq), 1e-14f * fro2);
        float c = 1.f, s = 0.f;
        if (apq * apq > thr) {
          float tau = (aqq - app) / (2.f * apq);
          float t = 1.f / (fabsf(tau) + sqrtf(1.f + tau * tau));
          t = (tau < 0.f) ? -t : t;
          c = 1.f / sqrtf(1.f + t * t);
          s = t * c;
          atomicAdd(&rotcnt_, 1);
        }
        cs_[tid] = c; sn_[tid] = s;
      }
      __syncthreads();
      for (int t = tid; t < 2048; t += 256) {
        int k = t >> 6, j = t & 63;
        int p = pp_[k], q = qq_[k]; float c = cs_[k], s = sn_[k];
        float ap = A[p][j], aq = A[q][j];
        A[p][j] = c * ap - s * aq;
        A[q][j] = s * ap + c * aq;
      }
      __syncthreads();
      for (int t = tid; t < 4096; t += 256) {
        int k = (t >> 6) & 31, j = t & 63;
        int p = pp_[k], q = qq_[k]; float c = cs_[k], s = sn_[k];
        if (t < 2048) {
          float ap = A[j][p], aq = A[j][q];
          A[j][p] = c * ap - s * aq;
          A[j][q] = s * ap + c * aq;
        } else {
          float vp = V[j][p], vq = V[j][q];
          V[j][p] = c * vp - s * vq;
          V[j][q] = s * vp + c * vq;
        }
      }
      __syncthreads();
    }
    int rc = rotcnt_;
    __syncthreads();
    if (rc == 0) break;
  }
}

__device__ void recon_write(const float (&V)[ND][PAD], const float* f, float* g,
                            int c, int wq) {
  float acc[16];
#pragma unroll
  for (int k = 0; k < 16; ++k) acc[k] = 0.f;
  for (int j = 0; j < ND; ++j) {
    float m = f[j] * V[c][j];
#pragma unroll
    for (int k = 0; k < 16; ++k) acc[k] = fmaf(V[wq + 4 * k][j], m, acc[k]);
  }
#pragma unroll
  for (int k = 0; k < 16; ++k) g[(wq + 4 * k) * ND + c] = acc[k];
}

// ---------------------------------------------------------------------------
// One-sided Jacobi, register-resident, hybrid VALU/DS exchange.
// lane = column; w[64] = column of W. XOR tournament r = 1..63.
// r<32: DPP(+permlane16_swap) on VALU; r>=32: ds_bpermute.
// All exchange paths are BIT-EXACT so paired lanes compute bitwise-identical
// rotation decisions (essential for consistency).
// ---------------------------------------------------------------------------
__device__ inline void jacobi1s(float (&w)[ND], int lane) {
  float g = 0.f;
#pragma unroll
  for (int i = 0; i < ND; ++i) g = fmaf(w[i], w[i], g);

  for (int sweep = 0; sweep < 18; ++sweep) {
    bool any = false;
    for (int r = 1; r < ND; ++r) {
      float v[ND + 1];  // v[64] carries the partner's g
      if (r >= 32) {
        int pa = ((lane ^ r) << 2);
#pragma unroll
        for (int i = 0; i < ND; ++i) v[i] = bperm_f(pa, w[i]);
        v[ND] = bperm_f(pa, g);
      } else {
        switch (r & 3) {
          case 0:
#pragma unroll
            for (int i = 0; i < ND; ++i) v[i] = w[i];
            v[ND] = g;
            break;
          case 1:
#pragma unroll
            for (int i = 0; i < ND; ++i) v[i] = dppf<0xB1>(w[i]);
            v[ND] = dppf<0xB1>(g);
            break;
          case 2:
#pragma unroll
            for (int i = 0; i < ND; ++i) v[i] = dppf<0x4E>(w[i]);
            v[ND] = dppf<0x4E>(g);
            break;
          default:
#pragma unroll
            for (int i = 0; i < ND; ++i) v[i] = dppf<0x1B>(w[i]);
            v[ND] = dppf<0x1B>(g);
            break;
        }
        if (r & 4) {  // ^4 = ^7 then ^3
#pragma unroll
          for (int i = 0; i <= ND; ++i) v[i] = dppf<0x1B>(dppf<0x141>(v[i]));
        }
        if (r & 8) {  // ^8 = ^15 then ^7
#pragma unroll
          for (int i = 0; i <= ND; ++i) v[i] = dppf<0x141>(dppf<0x140>(v[i]));
        }
        if (r & 16) {
#ifdef HAVE_PL16
#pragma unroll
          for (int i = 0; i <= ND; ++i) v[i] = pl16x(v[i]);
#else
          int pa16 = ((lane ^ 16) << 2);
#pragma unroll
          for (int i = 0; i <= ND; ++i) v[i] = bperm_f(pa16, v[i]);
#endif
        }
      }
      float gv = v[ND];
      // 4-accumulator dot (breaks the serial FMA chain; order symmetric)
      float a0 = 0.f, a1 = 0.f, a2 = 0.f, a3 = 0.f;
#pragma unroll
      for (int i = 0; i < ND; i += 4) {
        a0 = fmaf(w[i + 0], v[i + 0], a0);
        a1 = fmaf(w[i + 1], v[i + 1], a1);
        a2 = fmaf(w[i + 2], v[i + 2], a2);
        a3 = fmaf(w[i + 3], v[i + 3], a3);
      }
      float apq = (a0 + a1) + (a2 + a3);
      if (apq * apq > 4e-10f * g * gv) {
        int partner = lane ^ r;
        bool amP = lane < partner;
        float app = amP ? g : gv;
        float aqq = amP ? gv : g;
        float tau = (aqq - app) / (2.f * apq);
        float t = 1.f / (fabsf(tau) + sqrtf(1.f + tau * tau));
        t = (tau < 0.f) ? -t : t;
        float c = 1.f / sqrtf(1.f + t * t);
        float s = t * c;
        float s2 = amP ? -s : s;
#pragma unroll
        for (int i = 0; i < ND; ++i) w[i] = fmaf(s2, v[i], c * w[i]);
        float d = t * apq;
        g = amP ? (g - d) : (g + d);
        any = true;
      }
    }
    if (!__any(any)) break;
  }
}

// ---------------------------------------------------------------------------
// Batched congruence M = si*(x*si) per wave (lane = column).
//   x staged row-major + XOR-swizzled in LDS (b128-broadcast friendly).
//   step1: B[:,lane] = sum_a x_row_a * si[a][lane]   (x symmetric)
//   step2: M[:,lane] = sum_a si_row_a * B[a][lane]   (si rows via s_load, free)
// Leaves M in w_[64] registers. XL is clobbered (holds B transposed).
// ---------------------------------------------------------------------------
__device__ inline void congruence(const float* __restrict__ x_i,
                                  const float* __restrict__ si,
                                  float* __restrict__ XL, int lane,
                                  float (&w_)[ND]) {
  // stage: lane loads row `lane` of x, writes swizzled chunks
#pragma unroll
  for (int k = 0; k < 16; ++k) {
    float4 rv = ((const float4*)(x_i + lane * ND))[k];
    ((float4*)(XL + lane * ND))[k ^ (lane & 7)] = rv;
  }
  // step1
  float B[ND];
#pragma unroll
  for (int i = 0; i < ND; ++i) B[i] = 0.f;
  for (int a = 0; a < ND; ++a) {
    float sa = si[a * ND + lane];
    int ro = a * ND, sw = a & 7;
#pragma unroll
    for (int k = 0; k < 16; ++k) {
      const float4 c4 = *((const float4*)(XL + ro + ((k ^ sw) << 2)));
      B[4 * k + 0] = fmaf(c4.x, sa, B[4 * k + 0]);
      B[4 * k + 1] = fmaf(c4.y, sa, B[4 * k + 1]);
      B[4 * k + 2] = fmaf(c4.z, sa, B[4 * k + 2]);
      B[4 * k + 3] = fmaf(c4.w, sa, B[4 * k + 3]);
    }
  }
  // park B in LDS (transposed) to avoid runtime register indexing
#pragma unroll
  for (int a = 0; a < ND; ++a) XL[a * ND + lane] = B[a];
  // step2
#pragma unroll
  for (int i = 0; i < ND; ++i) w_[i] = 0.f;
  for (int a = 0; a < ND; ++a) {
    float ba = XL[a * ND + lane];
#pragma unroll
    for (int r2 = 0; r2 < ND; ++r2) w_[r2] = fmaf(si[a * ND + r2], ba, w_[r2]);
  }
}

// ---------------------------------------------------------------------------
// Kernels
// ---------------------------------------------------------------------------
__global__ __launch_bounds__(256) void k_mean_part(const float* __restrict__ x,
                                                   float* __restrict__ part) {
  int e = blockIdx.x * 256 + threadIdx.x;
  int chunk = blockIdx.y;
  const float* px = x + (size_t)chunk * 256 * NN + e;
  float s = 0.f;
  for (int i = 0; i < 256; ++i) s += px[(size_t)i * NN];
  part[(size_t)chunk * NN + e] = s;
}

__global__ __launch_bounds__(256) void k_mean_final(const float* __restrict__ part,
                                                    float* __restrict__ meanA) {
  int e = blockIdx.x * 256 + threadIdx.x;
  float s = 0.f;
  for (int c = 0; c < 32; ++c) s += part[(size_t)c * NN + e];
  meanA[e] = s * (1.f / (float)NB);
}

__global__ __launch_bounds__(256) void k_prep1(const float* __restrict__ meanA,
                                               const float* __restrict__ shift,
                                               float* __restrict__ s_out,
                                               float* __restrict__ si_out,
                                               float* __restrict__ ss_out) {
  __shared__ float A[ND][PAD], V[ND][PAD];
  __shared__ float f1[ND], f2[ND];
  int tid = threadIdx.x;
  const float* src = (blockIdx.x == 0) ? meanA : shift;
  for (int e = tid; e < NN; e += 256) A[e >> 6][e & 63] = src[e];
  for (int e = tid; e < NN; e += 256) V[e >> 6][e & 63] = ((e >> 6) == (e & 63)) ? 1.f : 0.f;
  jacobi2s(A, V, tid);
  if (tid < ND) {
    float wv = fmaxf(A[tid][tid], 1e-30f);
    f1[tid] = sqrtf(wv);
    f2[tid] = 1.f / sqrtf(wv);
  }
  __syncthreads();
  int c = tid & 63, wq = tid >> 6;
  if (blockIdx.x == 0) {
    recon_write(V, f1, s_out, c, wq);
    recon_write(V, f2, si_out, c, wq);
  } else {
    recon_write(V, f1, ss_out, c, wq);
  }
}

// batched Karcher tangent accumulation
__global__ __launch_bounds__(128, 2) void k_stage2(const float* __restrict__ x,
                                                   const float* __restrict__ si,
                                                   float* __restrict__ tPart,
                                                   int G2) {
  __shared__ float XLs[2][NN];
  __shared__ float lws[2][ND];
  int tid = threadIdx.x, lane = tid & 63, wv = tid >> 6;
  float* XL = XLs[wv];
  int wid = blockIdx.x * 2 + wv;
  int nw = G2 * 2;

  float tacc[ND];
#pragma unroll
  for (int i = 0; i < ND; ++i) tacc[i] = 0.f;

  for (int i = wid; i < NB; i += nw) {
    float w_[ND];
    congruence(x + (size_t)i * NN, si, XL, lane, w_);
    jacobi1s(w_, lane);
    float s2 = 0.f;
#pragma unroll
    for (int r2 = 0; r2 < ND; ++r2) s2 = fmaf(w_[r2], w_[r2], s2);
    float sig = sqrtf(fmaxf(s2, 1e-38f));
    float inv = 1.f / sig;
    lws[wv][lane] = logf(sig);
    // write U^T (row lane = own normalized column), swizzled like staging
#pragma unroll
    for (int k = 0; k < 16; ++k) {
      float4 uv;
      uv.x = w_[4 * k + 0] * inv;
      uv.y = w_[4 * k + 1] * inv;
      uv.z = w_[4 * k + 2] * inv;
      uv.w = w_[4 * k + 3] * inv;
      ((float4*)(XL + lane * ND))[k ^ (lane & 7)] = uv;
    }
    // tacc[r] += log(lam_j) * U[lane][j] * U[r][j]
    for (int j = 0; j < ND; ++j) {
      int ro = j * ND, sw = j & 7;
      float uj = XL[ro + (((lane >> 2) ^ sw) << 2) + (lane & 3)];
      float m = lws[wv][j] * uj;
#pragma unroll
      for (int k = 0; k < 16; ++k) {
        const float4 c4 = *((const float4*)(XL + ro + ((k ^ sw) << 2)));
        tacc[4 * k + 0] = fmaf(c4.x, m, tacc[4 * k + 0]);
        tacc[4 * k + 1] = fmaf(c4.y, m, tacc[4 * k + 1]);
        tacc[4 * k + 2] = fmaf(c4.z, m, tacc[4 * k + 2]);
        tacc[4 * k + 3] = fmaf(c4.w, m, tacc[4 * k + 3]);
      }
    }
  }
  // combine the block's two waves
  if (wv == 1) {
#pragma unroll
    for (int r2 = 0; r2 < ND; ++r2) XLs[1][r2 * ND + lane] = tacc[r2];
  }
  __syncthreads();
  if (wv == 0) {
#pragma unroll
    for (int r2 = 0; r2 < ND; ++r2) tacc[r2] += XLs[1][r2 * ND + lane];
#pragma unroll
    for (int r2 = 0; r2 < ND; ++r2)
      tPart[(size_t)blockIdx.x * NN + r2 * ND + lane] = tacc[r2];
  }
}

__global__ __launch_bounds__(256) void k_reduce_t(const float* __restrict__ tPart,
                                                  float* __restrict__ tbar, int G2) {
  int e = blockIdx.x * 256 + threadIdx.x;
  float s = 0.f;
  for (int b = 0; b < G2; ++b) s += tPart[(size_t)b * NN + e];
  tbar[e] = s * (1.f / (float)NB);
}

__global__ __launch_bounds__(256) void k_prep2(const float* __restrict__ tbar,
                                               const float* __restrict__ s_g,
                                               float* __restrict__ mi_out) {
  __shared__ float A[ND][PAD], V[ND][PAD];
  __shared__ float f1[ND];
  int tid = threadIdx.x;
  int c = tid & 63, wq = tid >> 6;
  for (int e = tid; e < NN; e += 256) A[e >> 6][e & 63] = tbar[e];
  for (int e = tid; e < NN; e += 256) V[e >> 6][e & 63] = ((e >> 6) == (e & 63)) ? 1.f : 0.f;
  jacobi2s(A, V, tid);
  if (tid < ND) f1[tid] = expf(A[tid][tid]);
  __syncthreads();
  {
    float acc[16];
#pragma unroll
    for (int k = 0; k < 16; ++k) acc[k] = 0.f;
    for (int j = 0; j < ND; ++j) {
      float m = f1[j] * V[c][j];
#pragma unroll
      for (int k = 0; k < 16; ++k) acc[k] = fmaf(V[wq + 4 * k][j], m, acc[k]);
    }
    __syncthreads();
#pragma unroll
    for (int k = 0; k < 16; ++k) A[wq + 4 * k][c] = acc[k];
  }
  __syncthreads();
  {
    float acc[16];
#pragma unroll
    for (int k = 0; k < 16; ++k) acc[k] = 0.f;
    for (int a = 0; a < ND; ++a) {
      float ea = A[a][c];
#pragma unroll
      for (int k = 0; k < 16; ++k) acc[k] = fmaf(s_g[(wq + 4 * k) * ND + a], ea, acc[k]);
    }
    __syncthreads();
#pragma unroll
    for (int k = 0; k < 16; ++k) V[wq + 4 * k][c] = acc[k];
  }
  __syncthreads();
  {
    float acc[16];
#pragma unroll
    for (int k = 0; k < 16; ++k) acc[k] = 0.f;
    for (int a = 0; a < ND; ++a) {
      float sa = s_g[a * ND + c];
#pragma unroll
      for (int k = 0; k < 16; ++k) acc[k] = fmaf(V[wq + 4 * k][a], sa, acc[k]);
    }
    __syncthreads();
#pragma unroll
    for (int k = 0; k < 16; ++k) A[wq + 4 * k][c] = acc[k];
  }
  __syncthreads();
  for (int e = tid; e < NN; e += 256) V[e >> 6][e & 63] = ((e >> 6) == (e & 63)) ? 1.f : 0.f;
  jacobi2s(A, V, tid);
  if (tid < ND) f1[tid] = 1.f / sqrtf(fmaxf(A[tid][tid], 1e-30f));
  __syncthreads();
  recon_write(V, f1, mi_out, c, wq);
}

// batched: W = mi*x_i*mi, eigh -> lam, Aout = ss*U, var partials
__global__ __launch_bounds__(128, 2) void k_stage3(const float* __restrict__ x,
                                                   const float* __restrict__ mi,
                                                   const float* __restrict__ ss,
                                                   float* __restrict__ aout,
                                                   float* __restrict__ lam,
                                                   float* __restrict__ varPart) {
  __shared__ float XLs[2][NN];
  __shared__ float vred[2];
  int tid = threadIdx.x, lane = tid & 63, wv = tid >> 6;
  float* XL = XLs[wv];
  int wid = blockIdx.x * 2 + wv;
  int nw = gridDim.x * 2;
  float varacc = 0.f;

  for (int i = wid; i < NB; i += nw) {
    float w_[ND];
    congruence(x + (size_t)i * NN, mi, XL, lane, w_);
    jacobi1s(w_, lane);
    float s2 = 0.f;
#pragma unroll
    for (int r2 = 0; r2 < ND; ++r2) s2 = fmaf(w_[r2], w_[r2], s2);
    float sig = sqrtf(fmaxf(s2, 1e-38f));
    float inv = 1.f / sig;
    lam[(size_t)i * ND + lane] = sig;
    float lg = logf(sig);
    varacc = fmaf(lg, lg, varacc);
    // park U column in LDS (avoids runtime register indexing)
#pragma unroll
    for (int a = 0; a < ND; ++a) XL[a * ND + lane] = w_[a] * inv;
    float acc[ND];
#pragma unroll
    for (int r2 = 0; r2 < ND; ++r2) acc[r2] = 0.f;
    for (int a = 0; a < ND; ++a) {
      float ua = XL[a * ND + lane];
#pragma unroll
      for (int r2 = 0; r2 < ND; ++r2) acc[r2] = fmaf(ss[a * ND + r2], ua, acc[r2]);
    }
#pragma unroll
    for (int r2 = 0; r2 < ND; ++r2)
      aout[(size_t)i * NN + r2 * ND + lane] = acc[r2];
  }
  for (int o = 32; o; o >>= 1) varacc += __shfl_down(varacc, o);
  if (lane == 0) vred[wv] = varacc;
  __syncthreads();
  if (tid == 0) varPart[blockIdx.x] = vred[0] + vred[1];
}

__global__ __launch_bounds__(64) void k_pfinal(const float* __restrict__ varPart,
                                               const float* __restrict__ scale,
                                               float* __restrict__ pout) {
  int tid = threadIdx.x;
  float s = 0.f;
  for (int i = tid; i < 1024; i += 64) s += varPart[i];
  for (int o = 32; o; o >>= 1) s += __shfl_down(s, o);
  if (tid == 0) {
    float var = s * (1.f / (float)NB);
    float sd = sqrtf(var);
    pout[0] = scale[0] / (sd + 1e-5f);
  }
}

__global__ __launch_bounds__(256) void k_stage5(const float* __restrict__ ain,
                                                const float* __restrict__ lam,
                                                const float* __restrict__ pws,
                                                float* __restrict__ out) {
  __shared__ float Ab[ND][PAD];
  __shared__ float lp[ND];
  int tid = threadIdx.x;
  int i = blockIdx.x;
  for (int e = tid; e < NN; e += 256) Ab[e >> 6][e & 63] = ain[(size_t)i * NN + e];
  if (tid < ND) {
    float p = pws[0];
    lp[tid] = powf(lam[(size_t)i * ND + tid], p);
  }
  __syncthreads();
  int c = tid & 63, wq = tid >> 6;
  float acc[16];
#pragma unroll
  for (int k = 0; k < 16; ++k) acc[k] = 0.f;
  for (int j = 0; j < ND; ++j) {
    float m = lp[j] * Ab[c][j];
#pragma unroll
    for (int k = 0; k < 16; ++k) acc[k] = fmaf(Ab[wq + 4 * k][j], m, acc[k]);
  }
#pragma unroll
  for (int k = 0; k < 16; ++k)
    out[(size_t)i * NN + (wq + 4 * k) * ND + c] = acc[k];
}

// ---------------------------------------------------------------------------
extern "C" void kernel_launch(void* const* d_in, const int* in_sizes, int n_in,
                              void* d_out, int out_size, void* d_ws, size_t ws_size,
                              hipStream_t stream) {
  const float* x     = (const float*)d_in[0];
  const float* shift = (const float*)d_in[1];
  const float* scale = (const float*)d_in[2];
  float* out = (float*)d_out;
  float* ws  = (float*)d_ws;
  (void)in_sizes; (void)n_in; (void)out_size;

  size_t wsf = ws_size / 4;
  int G2 = 1024;
  if (OFF_TPART + (size_t)G2 * NN > wsf) {
    size_t avail = (wsf > OFF_TPART) ? (wsf - OFF_TPART) / NN : 1;
    if (avail < 1) avail = 1;
    if (avail < (size_t)G2) G2 = (int)avail;
  }

  k_mean_part<<<dim3(16, 32), 256, 0, stream>>>(x, ws + OFF_MEANPART);
  k_mean_final<<<16, 256, 0, stream>>>(ws + OFF_MEANPART, ws + OFF_MEANA);
  k_prep1<<<2, 256, 0, stream>>>(ws + OFF_MEANA, shift, ws + OFF_S, ws + OFF_SI,
                                 ws + OFF_SS);
  k_stage2<<<G2, 128, 0, stream>>>(x, ws + OFF_SI, ws + OFF_TPART, G2);
  k_reduce_t<<<16, 256, 0, stream>>>(ws + OFF_TPART, ws + OFF_TBAR, G2);
  k_prep2<<<1, 256, 0, stream>>>(ws + OFF_TBAR, ws + OFF_S, ws + OFF_MI);
  k_stage3<<<1024, 128, 0, stream>>>(x, ws + OFF_MI, ws + OFF_SS, out,
                                     ws + OFF_LAM, ws + OFF_VARPART);
  k_pfinal<<<1, 64, 0, stream>>>(ws + OFF_VARPART, scale, ws + OFF_P);
  k_stage5<<<8192, 256, 0, stream>>>(out, ws + OFF_LAM, ws + OFF_P, out);
}

// Round 3
// 14984.126 us; speedup vs baseline: 1.5223x; 1.5223x over previous
//
#include <hip/hip_runtime.h>
#include <math.h>

#define ND 64
#define PAD 65
#define NN 4096
#define NB 8192

// ws layout (floats)
#define OFF_MEANPART ((size_t)0)        // 32*4096
#define OFF_MEANA    ((size_t)131072)
#define OFF_S        ((size_t)135168)
#define OFF_SI       ((size_t)139264)
#define OFF_SS       ((size_t)143360)
#define OFF_TBAR     ((size_t)147456)
#define OFF_MI       ((size_t)151552)
#define OFF_P        ((size_t)155648)
#define OFF_VARPART  ((size_t)155712)   // 2048 slots
#define OFF_LAM      ((size_t)157760)   // NB*ND = 524288
#define OFF_TPART    ((size_t)682048)   // NW*4096 per-wave partials

#define G2_BLOCKS 1024
#define G3_BLOCKS 1536

// ---------------------------------------------------------------------------
// lane-exchange primitives
// ---------------------------------------------------------------------------
template<int CTRL>
__device__ __forceinline__ float dppf(float x) {
  return __builtin_bit_cast(float,
      __builtin_amdgcn_mov_dpp(__builtin_bit_cast(int, x), CTRL, 0xF, 0xF, true));
}
__device__ __forceinline__ float bperm_f(int pa, float x) {
  return __builtin_bit_cast(float,
      __builtin_amdgcn_ds_bpermute(pa, __builtin_bit_cast(int, x)));
}

// XOR-exchange of w[0..63] and g via 1-2 DPP ops (bit-exact lane^R).
// ctrls: ^1=0xB1 ^2=0x4E ^3=0x1B ^7=0x141(row_half_mirror) ^15=0x140(row_mirror)
template<int R>
__device__ __forceinline__ void exch_dpp(const float (&w)[ND], float g,
                                         float (&v)[ND + 1]) {
#pragma unroll
  for (int i = 0; i <= ND; ++i) {
    float s = (i < ND) ? w[i] : g;
    float t;
    if constexpr (R == 1)  t = dppf<0xB1>(s);
    else if constexpr (R == 2)  t = dppf<0x4E>(s);
    else if constexpr (R == 3)  t = dppf<0x1B>(s);
    else if constexpr (R == 7)  t = dppf<0x141>(s);
    else if constexpr (R == 15) t = dppf<0x140>(s);
    else if constexpr (R == 4)  t = dppf<0x1B>(dppf<0x141>(s));   // 3^7
    else if constexpr (R == 5)  t = dppf<0x4E>(dppf<0x141>(s));   // 2^7
    else if constexpr (R == 6)  t = dppf<0xB1>(dppf<0x141>(s));   // 1^7
    else if constexpr (R == 8)  t = dppf<0x141>(dppf<0x140>(s));  // 7^15
    else                        t = dppf<0x1B>(dppf<0x140>(s));   // 12 = 3^15
    asm volatile("" : "+v"(t));  // pin: forbid rematerialization
    v[i] = t;
  }
}

// ---------------------------------------------------------------------------
// Two-sided LDS Jacobi (256 threads, one 64x64 matrix) for the few singles.
// ---------------------------------------------------------------------------
__device__ void jacobi2s(float (&A)[ND][PAD], float (&V)[ND][PAD], int tid) {
  __shared__ float cs_[32], sn_[32];
  __shared__ int   pp_[32], qq_[32];
  __shared__ int   rotcnt_;
  __shared__ float fro2_;
  __shared__ float red_[4];

  __syncthreads();
  float loc = 0.f;
  for (int e = tid; e < NN; e += 256) { float a = A[e >> 6][e & 63]; loc += a * a; }
  for (int o = 32; o; o >>= 1) loc += __shfl_down(loc, o);
  if ((tid & 63) == 0) red_[tid >> 6] = loc;
  __syncthreads();
  if (tid == 0) fro2_ = red_[0] + red_[1] + red_[2] + red_[3];
  __syncthreads();
  float fro2 = fro2_;

  for (int sweep = 0; sweep < 20; ++sweep) {
    if (tid == 0) rotcnt_ = 0;
    __syncthreads();
    for (int r = 0; r < 63; ++r) {
      if (tid < 32) {
        int p, q;
        if (tid == 0) { p = 63; q = r; }
        else { p = (r + tid) % 63; q = (r + 63 - tid) % 63; }
        if (p > q) { int t0 = p; p = q; q = t0; }
        pp_[tid] = p; qq_[tid] = q;
        float app = A[p][p], aqq = A[q][q], apq = A[p][q];
        float thr = fmaxf(1e-12f * fabsf(app * aqq), 1e-14f * fro2);
        float c = 1.f, s = 0.f;
        if (apq * apq > thr) {
          float tau = (aqq - app) / (2.f * apq);
          float t = 1.f / (fabsf(tau) + sqrtf(1.f + tau * tau));
          t = (tau < 0.f) ? -t : t;
          c = 1.f / sqrtf(1.f + t * t);
          s = t * c;
          atomicAdd(&rotcnt_, 1);
        }
        cs_[tid] = c; sn_[tid] = s;
      }
      __syncthreads();
      for (int t = tid; t < 2048; t += 256) {
        int k = t >> 6, j = t & 63;
        int p = pp_[k], q = qq_[k]; float c = cs_[k], s = sn_[k];
        float ap = A[p][j], aq = A[q][j];
        A[p][j] = c * ap - s * aq;
        A[q][j] = s * ap + c * aq;
      }
      __syncthreads();
      for (int t = tid; t < 4096; t += 256) {
        int k = (t >> 6) & 31, j = t & 63;
        int p = pp_[k], q = qq_[k]; float c = cs_[k], s = sn_[k];
        if (t < 2048) {
          float ap = A[j][p], aq = A[j][q];
          A[j][p] = c * ap - s * aq;
          A[j][q] = s * ap + c * aq;
        } else {
          float vp = V[j][p], vq = V[j][q];
          V[j][p] = c * vp - s * vq;
          V[j][q] = s * vp + c * vq;
        }
      }
      __syncthreads();
    }
    int rc = rotcnt_;
    __syncthreads();
    if (rc == 0) break;
  }
}

__device__ void recon_write(const float (&V)[ND][PAD], const float* f, float* g,
                            int c, int wq) {
  float acc[16];
#pragma unroll
  for (int k = 0; k < 16; ++k) acc[k] = 0.f;
  for (int j = 0; j < ND; ++j) {
    float m = f[j] * V[c][j];
#pragma unroll
    for (int k = 0; k < 16; ++k) acc[k] = fmaf(V[wq + 4 * k][j], m, acc[k]);
  }
#pragma unroll
  for (int k = 0; k < 16; ++k) g[(wq + 4 * k) * ND + c] = acc[k];
}

// ---------------------------------------------------------------------------
// One-sided Jacobi, register-resident. lane = column; w[64] = own column.
// XOR tournament r = 1..63. Rounds in {1..8,12,15} exchange on the VALU
// (1-2 independent DPP ops/element); the rest use ds_bpermute with the
// results PINNED live (asm) so the compiler cannot re-issue the exchange
// for the update (remat doubled DS traffic in the round-1 kernel).
// ---------------------------------------------------------------------------
__device__ inline void jacobi1s(float (&w)[ND], int lane) {
  float g = 0.f;
#pragma unroll
  for (int i = 0; i < ND; ++i) g = fmaf(w[i], w[i], g);

  for (int sweep = 0; sweep < 18; ++sweep) {
    bool any = false;
    for (int r = 1; r < ND; ++r) {
      float v[ND + 1];  // v[64] = partner's g
      switch (r) {
        case 1:  exch_dpp<1>(w, g, v); break;
        case 2:  exch_dpp<2>(w, g, v); break;
        case 3:  exch_dpp<3>(w, g, v); break;
        case 4:  exch_dpp<4>(w, g, v); break;
        case 5:  exch_dpp<5>(w, g, v); break;
        case 6:  exch_dpp<6>(w, g, v); break;
        case 7:  exch_dpp<7>(w, g, v); break;
        case 8:  exch_dpp<8>(w, g, v); break;
        case 12: exch_dpp<12>(w, g, v); break;
        case 15: exch_dpp<15>(w, g, v); break;
        default: {
          int pa = (lane ^ r) << 2;
#pragma unroll
          for (int i = 0; i <= ND; ++i) {
            float t = bperm_f(pa, (i < ND) ? w[i] : g);
            asm volatile("" : "+v"(t));  // pin: keep live, no re-issue
            v[i] = t;
          }
        }
      }
      float gv = v[ND];
      float a0 = 0.f, a1 = 0.f, a2 = 0.f, a3 = 0.f;
#pragma unroll
      for (int i = 0; i < ND; i += 4) {
        a0 = fmaf(w[i + 0], v[i + 0], a0);
        a1 = fmaf(w[i + 1], v[i + 1], a1);
        a2 = fmaf(w[i + 2], v[i + 2], a2);
        a3 = fmaf(w[i + 3], v[i + 3], a3);
      }
      float apq = (a0 + a1) + (a2 + a3);
      if (apq * apq > 4e-10f * g * gv) {
        int partner = lane ^ r;
        bool amP = lane < partner;
        float app = amP ? g : gv;
        float aqq = amP ? gv : g;
        float tau = (aqq - app) / (2.f * apq);
        float t = 1.f / (fabsf(tau) + sqrtf(1.f + tau * tau));
        t = (tau < 0.f) ? -t : t;
        float c = 1.f / sqrtf(1.f + t * t);
        float s = t * c;
        float s2 = amP ? -s : s;
#pragma unroll
        for (int i = 0; i < ND; ++i) w[i] = fmaf(s2, v[i], c * w[i]);
        float d = t * apq;
        g = amP ? (g - d) : (g + d);
        any = true;
      }
    }
    if (!__any(any)) break;
  }
}

// ---------------------------------------------------------------------------
// Congruence M = si*(x*si), lane = column of M, using an 8KB LDS buffer.
// Two-pass staging of x (32 rows at a time, chunk-swizzled for writes,
// broadcast b128 reads), B kept in registers, step2 via half-parking B
// (runtime row index must come from LDS, not registers).
// XL: 2048 floats per wave.
// ---------------------------------------------------------------------------
__device__ inline void congruence2(const float* __restrict__ x_i,
                                   const float* __restrict__ si,
                                   float* __restrict__ XL, int lane,
                                   float (&w_)[ND]) {
  float B[ND];
#pragma unroll
  for (int i = 0; i < ND; ++i) B[i] = 0.f;

  for (int p = 0; p < 2; ++p) {
    // stage rows [32p, 32p+32): 512 float4 chunks, coalesced reads
#pragma unroll
    for (int k = 0; k < 8; ++k) {
      int m = k * 64 + lane;
      float4 rv = ((const float4*)(x_i + p * 2048))[m];
      int phys = m ^ ((m >> 4) & 7);
      ((float4*)XL)[phys] = rv;
    }
    // B[r] += sum_a x[a][r] * si[a][lane]   (x symmetric)
    for (int a0 = 0; a0 < 32; ++a0) {
      int a = p * 32 + a0;
      float sa = si[a * ND + lane];
      int base = a0 * 16, sw = a0 & 7;
#pragma unroll
      for (int k = 0; k < 16; ++k) {
        const float4 c4 = ((const float4*)XL)[base + (k ^ sw)];
        B[4 * k + 0] = fmaf(c4.x, sa, B[4 * k + 0]);
        B[4 * k + 1] = fmaf(c4.y, sa, B[4 * k + 1]);
        B[4 * k + 2] = fmaf(c4.z, sa, B[4 * k + 2]);
        B[4 * k + 3] = fmaf(c4.w, sa, B[4 * k + 3]);
      }
    }
  }
  // step2: w_[r] = sum_a si[r][a] * B[a][lane], B parked in halves (8KB)
#pragma unroll
  for (int i = 0; i < ND; ++i) w_[i] = 0.f;
  for (int h = 0; h < 2; ++h) {
#pragma unroll
    for (int j = 0; j < 32; ++j) XL[j * ND + lane] = B[h * 32 + j];
    for (int a0 = 0; a0 < 32; ++a0) {
      float ba = XL[a0 * ND + lane];
      const float* sir = si + (h * 32 + a0) * ND;
#pragma unroll
      for (int r2 = 0; r2 < ND; ++r2) w_[r2] = fmaf(sir[r2], ba, w_[r2]);
    }
  }
}

// ---------------------------------------------------------------------------
// Kernels
// ---------------------------------------------------------------------------
__global__ __launch_bounds__(256) void k_mean_part(const float* __restrict__ x,
                                                   float* __restrict__ part) {
  int e = blockIdx.x * 256 + threadIdx.x;
  int chunk = blockIdx.y;
  const float* px = x + (size_t)chunk * 256 * NN + e;
  float s = 0.f;
  for (int i = 0; i < 256; ++i) s += px[(size_t)i * NN];
  part[(size_t)chunk * NN + e] = s;
}

__global__ __launch_bounds__(256) void k_mean_final(const float* __restrict__ part,
                                                    float* __restrict__ meanA) {
  int e = blockIdx.x * 256 + threadIdx.x;
  float s = 0.f;
  for (int c = 0; c < 32; ++c) s += part[(size_t)c * NN + e];
  meanA[e] = s * (1.f / (float)NB);
}

__global__ __launch_bounds__(256) void k_prep1(const float* __restrict__ meanA,
                                               const float* __restrict__ shift,
                                               float* __restrict__ s_out,
                                               float* __restrict__ si_out,
                                               float* __restrict__ ss_out) {
  __shared__ float A[ND][PAD], V[ND][PAD];
  __shared__ float f1[ND], f2[ND];
  int tid = threadIdx.x;
  const float* src = (blockIdx.x == 0) ? meanA : shift;
  for (int e = tid; e < NN; e += 256) A[e >> 6][e & 63] = src[e];
  for (int e = tid; e < NN; e += 256) V[e >> 6][e & 63] = ((e >> 6) == (e & 63)) ? 1.f : 0.f;
  jacobi2s(A, V, tid);
  if (tid < ND) {
    float wv = fmaxf(A[tid][tid], 1e-30f);
    f1[tid] = sqrtf(wv);
    f2[tid] = 1.f / sqrtf(wv);
  }
  __syncthreads();
  int c = tid & 63, wq = tid >> 6;
  if (blockIdx.x == 0) {
    recon_write(V, f1, s_out, c, wq);
    recon_write(V, f2, si_out, c, wq);
  } else {
    recon_write(V, f1, ss_out, c, wq);
  }
}

// batched Karcher tangent accumulation; per-WAVE partial rows in tPart
__global__ __launch_bounds__(128, 2) void k_stage2(const float* __restrict__ x,
                                                   const float* __restrict__ si,
                                                   float* __restrict__ tPart,
                                                   int G2) {
  __shared__ float XLs[2][2048];
  __shared__ float lws[2][ND];
  int tid = threadIdx.x, lane = tid & 63, wv = tid >> 6;
  float* XL = XLs[wv];
  int wid = blockIdx.x * 2 + wv;
  int nw = G2 * 2;

  float tacc[ND];
#pragma unroll
  for (int i = 0; i < ND; ++i) tacc[i] = 0.f;

  for (int i = wid; i < NB; i += nw) {
    float w_[ND];
    congruence2(x + (size_t)i * NN, si, XL, lane, w_);
    jacobi1s(w_, lane);
    float s2 = 0.f;
#pragma unroll
    for (int r2 = 0; r2 < ND; ++r2) s2 = fmaf(w_[r2], w_[r2], s2);
    float sig = sqrtf(fmaxf(s2, 1e-38f));
    float inv = 1.f / sig;
    lws[wv][lane] = logf(sig);
    // tangent: tacc[r] += log(lam_j) U[r][j] U[lane][j], staged in column halves
    for (int h = 0; h < 2; ++h) {
      if ((lane >> 5) == h) {
        int jc = lane & 31;
#pragma unroll
        for (int k = 0; k < 16; ++k) {
          float4 uv;
          uv.x = w_[4 * k + 0] * inv;
          uv.y = w_[4 * k + 1] * inv;
          uv.z = w_[4 * k + 2] * inv;
          uv.w = w_[4 * k + 3] * inv;
          ((float4*)XL)[jc * 16 + (k ^ (jc & 7))] = uv;
        }
      }
      for (int j2 = 0; j2 < 32; ++j2) {
        int sw = j2 & 7;
        float uj = XL[(j2 * 16 + ((lane >> 2) ^ sw)) * 4 + (lane & 3)];
        float m = lws[wv][h * 32 + j2] * uj;
#pragma unroll
        for (int k = 0; k < 16; ++k) {
          const float4 c4 = ((const float4*)XL)[j2 * 16 + (k ^ sw)];
          tacc[4 * k + 0] = fmaf(c4.x, m, tacc[4 * k + 0]);
          tacc[4 * k + 1] = fmaf(c4.y, m, tacc[4 * k + 1]);
          tacc[4 * k + 2] = fmaf(c4.z, m, tacc[4 * k + 2]);
          tacc[4 * k + 3] = fmaf(c4.w, m, tacc[4 * k + 3]);
        }
      }
    }
  }
#pragma unroll
  for (int r2 = 0; r2 < ND; ++r2)
    tPart[(size_t)wid * NN + r2 * ND + lane] = tacc[r2];
}

__global__ __launch_bounds__(256) void k_reduce_t(const float* __restrict__ tPart,
                                                  float* __restrict__ tbar, int nw) {
  int e = blockIdx.x * 256 + threadIdx.x;
  float s = 0.f;
  for (int b = 0; b < nw; ++b) s += tPart[(size_t)b * NN + e];
  tbar[e] = s * (1.f / (float)NB);
}

__global__ __launch_bounds__(256) void k_prep2(const float* __restrict__ tbar,
                                               const float* __restrict__ s_g,
                                               float* __restrict__ mi_out) {
  __shared__ float A[ND][PAD], V[ND][PAD];
  __shared__ float f1[ND];
  int tid = threadIdx.x;
  int c = tid & 63, wq = tid >> 6;
  for (int e = tid; e < NN; e += 256) A[e >> 6][e & 63] = tbar[e];
  for (int e = tid; e < NN; e += 256) V[e >> 6][e & 63] = ((e >> 6) == (e & 63)) ? 1.f : 0.f;
  jacobi2s(A, V, tid);
  if (tid < ND) f1[tid] = expf(A[tid][tid]);
  __syncthreads();
  {
    float acc[16];
#pragma unroll
    for (int k = 0; k < 16; ++k) acc[k] = 0.f;
    for (int j = 0; j < ND; ++j) {
      float m = f1[j] * V[c][j];
#pragma unroll
      for (int k = 0; k < 16; ++k) acc[k] = fmaf(V[wq + 4 * k][j], m, acc[k]);
    }
    __syncthreads();
#pragma unroll
    for (int k = 0; k < 16; ++k) A[wq + 4 * k][c] = acc[k];
  }
  __syncthreads();
  {
    float acc[16];
#pragma unroll
    for (int k = 0; k < 16; ++k) acc[k] = 0.f;
    for (int a = 0; a < ND; ++a) {
      float ea = A[a][c];
#pragma unroll
      for (int k = 0; k < 16; ++k) acc[k] = fmaf(s_g[(wq + 4 * k) * ND + a], ea, acc[k]);
    }
    __syncthreads();
#pragma unroll
    for (int k = 0; k < 16; ++k) V[wq + 4 * k][c] = acc[k];
  }
  __syncthreads();
  {
    float acc[16];
#pragma unroll
    for (int k = 0; k < 16; ++k) acc[k] = 0.f;
    for (int a = 0; a < ND; ++a) {
      float sa = s_g[a * ND + c];
#pragma unroll
      for (int k = 0; k < 16; ++k) acc[k] = fmaf(V[wq + 4 * k][a], sa, acc[k]);
    }
    __syncthreads();
#pragma unroll
    for (int k = 0; k < 16; ++k) A[wq + 4 * k][c] = acc[k];
  }
  __syncthreads();
  for (int e = tid; e < NN; e += 256) V[e >> 6][e & 63] = ((e >> 6) == (e & 63)) ? 1.f : 0.f;
  jacobi2s(A, V, tid);
  if (tid < ND) f1[tid] = 1.f / sqrtf(fmaxf(A[tid][tid], 1e-30f));
  __syncthreads();
  recon_write(V, f1, mi_out, c, wq);
}

// batched: W = mi*x_i*mi, eigh -> lam, Aout = ss*U, var partials
__global__ __launch_bounds__(128, 3) void k_stage3(const float* __restrict__ x,
                                                   const float* __restrict__ mi,
                                                   const float* __restrict__ ss,
                                                   float* __restrict__ aout,
                                                   float* __restrict__ lam,
                                                   float* __restrict__ varPart) {
  __shared__ float XLs[2][2048];
  __shared__ float vred[2];
  int tid = threadIdx.x, lane = tid & 63, wv = tid >> 6;
  float* XL = XLs[wv];
  int wid = blockIdx.x * 2 + wv;
  int nw = gridDim.x * 2;
  float varacc = 0.f;

  for (int i = wid; i < NB; i += nw) {
    float w_[ND];
    congruence2(x + (size_t)i * NN, mi, XL, lane, w_);
    jacobi1s(w_, lane);
    float s2 = 0.f;
#pragma unroll
    for (int r2 = 0; r2 < ND; ++r2) s2 = fmaf(w_[r2], w_[r2], s2);
    float sig = sqrtf(fmaxf(s2, 1e-38f));
    float inv = 1.f / sig;
    lam[(size_t)i * ND + lane] = sig;
    float lg = logf(sig);
    varacc = fmaf(lg, lg, varacc);
    // Aout[:,lane] = ss * U[:,lane], U parked in halves (runtime row idx)
    float acc[ND];
#pragma unroll
    for (int r2 = 0; r2 < ND; ++r2) acc[r2] = 0.f;
    for (int h = 0; h < 2; ++h) {
#pragma unroll
      for (int j = 0; j < 32; ++j) XL[j * ND + lane] = w_[h * 32 + j] * inv;
      for (int a0 = 0; a0 < 32; ++a0) {
        float ua = XL[a0 * ND + lane];
        const float* ssr = ss + (h * 32 + a0) * ND;
#pragma unroll
        for (int r2 = 0; r2 < ND; ++r2) acc[r2] = fmaf(ssr[r2], ua, acc[r2]);
      }
    }
#pragma unroll
    for (int r2 = 0; r2 < ND; ++r2)
      aout[(size_t)i * NN + r2 * ND + lane] = acc[r2];
  }
  for (int o = 32; o; o >>= 1) varacc += __shfl_down(varacc, o);
  if (lane == 0) vred[wv] = varacc;
  __syncthreads();
  if (tid == 0) varPart[blockIdx.x] = vred[0] + vred[1];
}

__global__ __launch_bounds__(64) void k_pfinal(const float* __restrict__ varPart,
                                               const float* __restrict__ scale,
                                               float* __restrict__ pout, int n) {
  int tid = threadIdx.x;
  float s = 0.f;
  for (int i = tid; i < n; i += 64) s += varPart[i];
  for (int o = 32; o; o >>= 1) s += __shfl_down(s, o);
  if (tid == 0) {
    float var = s * (1.f / (float)NB);
    float sd = sqrtf(var);
    pout[0] = scale[0] / (sd + 1e-5f);
  }
}

__global__ __launch_bounds__(256) void k_stage5(const float* __restrict__ ain,
                                                const float* __restrict__ lam,
                                                const float* __restrict__ pws,
                                                float* __restrict__ out) {
  __shared__ float Ab[ND][PAD];
  __shared__ float lp[ND];
  int tid = threadIdx.x;
  int i = blockIdx.x;
  for (int e = tid; e < NN; e += 256) Ab[e >> 6][e & 63] = ain[(size_t)i * NN + e];
  if (tid < ND) {
    float p = pws[0];
    lp[tid] = powf(lam[(size_t)i * ND + tid], p);
  }
  __syncthreads();
  int c = tid & 63, wq = tid >> 6;
  float acc[16];
#pragma unroll
  for (int k = 0; k < 16; ++k) acc[k] = 0.f;
  for (int j = 0; j < ND; ++j) {
    float m = lp[j] * Ab[c][j];
#pragma unroll
    for (int k = 0; k < 16; ++k) acc[k] = fmaf(Ab[wq + 4 * k][j], m, acc[k]);
  }
#pragma unroll
  for (int k = 0; k < 16; ++k)
    out[(size_t)i * NN + (wq + 4 * k) * ND + c] = acc[k];
}

// ---------------------------------------------------------------------------
extern "C" void kernel_launch(void* const* d_in, const int* in_sizes, int n_in,
                              void* d_out, int out_size, void* d_ws, size_t ws_size,
                              hipStream_t stream) {
  const float* x     = (const float*)d_in[0];
  const float* shift = (const float*)d_in[1];
  const float* scale = (const float*)d_in[2];
  float* out = (float*)d_out;
  float* ws  = (float*)d_ws;
  (void)in_sizes; (void)n_in; (void)out_size;

  size_t wsf = ws_size / 4;
  int G2 = G2_BLOCKS;
  if (OFF_TPART + (size_t)(2 * G2) * NN > wsf) {
    size_t avail = (wsf > OFF_TPART) ? (wsf - OFF_TPART) / (2 * NN) : 1;
    if (avail < 1) avail = 1;
    if (avail < (size_t)G2) G2 = (int)avail;
  }

  k_mean_part<<<dim3(16, 32), 256, 0, stream>>>(x, ws + OFF_MEANPART);
  k_mean_final<<<16, 256, 0, stream>>>(ws + OFF_MEANPART, ws + OFF_MEANA);
  k_prep1<<<2, 256, 0, stream>>>(ws + OFF_MEANA, shift, ws + OFF_S, ws + OFF_SI,
                                 ws + OFF_SS);
  k_stage2<<<G2, 128, 0, stream>>>(x, ws + OFF_SI, ws + OFF_TPART, G2);
  k_reduce_t<<<16, 256, 0, stream>>>(ws + OFF_TPART, ws + OFF_TBAR, 2 * G2);
  k_prep2<<<1, 256, 0, stream>>>(ws + OFF_TBAR, ws + OFF_S, ws + OFF_MI);
  k_stage3<<<G3_BLOCKS, 128, 0, stream>>>(x, ws + OFF_MI, ws + OFF_SS, out,
                                          ws + OFF_LAM, ws + OFF_VARPART);
  k_pfinal<<<1, 64, 0, stream>>>(ws + OFF_VARPART, scale, ws + OFF_P, G3_BLOCKS);
  k_stage5<<<8192, 256, 0, stream>>>(out, ws + OFF_LAM, ws + OFF_P, out);
}